// Round 1
// baseline (3739.363 us; speedup 1.0000x reference)
//
#include <hip/hip_runtime.h>
#include <cmath>

// Problem dims (fixed by reference)
#define B_   128
#define T_   40
#define E_   512
#define H_   1024
#define V_   10000
#define IN_  2048
#define G4_  4096   // 4*H

// ---------------------------------------------------------------------------
// zero init: hs_full[0] (h at t=0) and cbuf[0] (c at t=0), each 128*1024 floats
// ---------------------------------------------------------------------------
__global__ __launch_bounds__(256) void zero_kernel(float* __restrict__ a,
                                                   float* __restrict__ b) {
    int i = blockIdx.x * 256 + threadIdx.x;   // grid 512 -> 131072 threads
    a[i] = 0.f;
    b[i] = 0.f;
}

// ---------------------------------------------------------------------------
// feats[b][e] = dot(X[b][:], fembed_w[e][:]) + fembed_b[e]
// grid (128 b, 2 e-groups), block 256: one X row staged in LDS per block
// ---------------------------------------------------------------------------
__global__ __launch_bounds__(256) void feats_kernel(const float* __restrict__ X,
                                                    const float* __restrict__ W,
                                                    const float* __restrict__ bias,
                                                    float* __restrict__ out) {
    __shared__ float xs[IN_];
    int b = blockIdx.x, eg = blockIdx.y;
    const float4* xr = (const float4*)(X + (size_t)b * IN_);
    for (int i = threadIdx.x; i < IN_ / 4; i += 256)
        ((float4*)xs)[i] = xr[i];
    __syncthreads();
    int e = eg * 256 + threadIdx.x;
    const float* wr = W + (size_t)e * IN_;
    float acc = 0.f;
#pragma unroll 4
    for (int k = 0; k < IN_; k += 4) {
        float4 w = *(const float4*)(wr + k);
        acc += w.x * xs[k] + w.y * xs[k + 1] + w.z * xs[k + 2] + w.w * xs[k + 3];
    }
    out[(size_t)b * E_ + e] = acc + bias[e];
}

// ---------------------------------------------------------------------------
// gfeat[b][g] = dot(feats[b][:], w_ih[g][0:512]) + b_ih[g]   (t-invariant part)
// grid (16 b-groups, 16 g-groups), block 256; thread: 8 b x 1 g
// ---------------------------------------------------------------------------
__global__ __launch_bounds__(256) void gfeat_kernel(const float* __restrict__ feats,
                                                    const float* __restrict__ w_ih,
                                                    const float* __restrict__ b_ih,
                                                    float* __restrict__ gfeat) {
    __shared__ float fs[8][E_];          // 16 KB
    int bg = blockIdx.x * 8, gg = blockIdx.y * 256;
    for (int i = threadIdx.x; i < 8 * E_ / 4; i += 256) {
        int b = i / (E_ / 4), k4 = i % (E_ / 4);
        ((float4*)fs[b])[k4] = ((const float4*)(feats + (size_t)(bg + b) * E_))[k4];
    }
    __syncthreads();
    int g = gg + threadIdx.x;
    const float* wr = w_ih + (size_t)g * (2 * E_);   // first E_ cols = feats part
    float acc[8] = {};
    for (int k = 0; k < E_; k += 4) {
        float4 w = *(const float4*)(wr + k);
#pragma unroll
        for (int b = 0; b < 8; ++b) {
            float4 f = *(const float4*)&fs[b][k];
            acc[b] += w.x * f.x + w.y * f.y + w.z * f.z + w.w * f.w;
        }
    }
    float bb = b_ih[g];
#pragma unroll
    for (int b = 0; b < 8; ++b)
        gfeat[(size_t)(bg + b) * G4_ + g] = acc[b] + bb;
}

// ---------------------------------------------------------------------------
// emb[m][:] = lembed[labels[b][t]][:], m = t*128+b  (A matrix for gemb GEMM)
// ---------------------------------------------------------------------------
__global__ __launch_bounds__(128) void gather_kernel(const int* __restrict__ labels,
                                                     const float* __restrict__ lembed,
                                                     float* __restrict__ emb) {
    int m = blockIdx.x;                       // 5120 blocks
    int t = m >> 7, b = m & 127;
    int lab = labels[b * T_ + t];
    const float4* src = (const float4*)(lembed + (size_t)lab * E_);
    float4* dst = (float4*)(emb + (size_t)m * E_);
    dst[threadIdx.x] = src[threadIdx.x];      // 128 * float4 = 512 floats
}

// ---------------------------------------------------------------------------
// Generic fp32 GEMM, C[M][N] = A[M][lda(K)] * B[N][ldb(K)]^T (+ epilogue)
// Tile 128x128, BK=16, 256 threads, 8x8 per thread.
// EPI 0: gx epilogue  -> C[m*N+n] = acc + bias[(m&127)*N + n]   (rowbias gfeat)
// EPI 1: logits       -> out[b][t][n] = acc + bias[n], m=(t*128+b), guard n<N
// ---------------------------------------------------------------------------
template <int EPI>
__global__ __launch_bounds__(256) void gemm_f32(const float* __restrict__ A, int lda,
                                                const float* __restrict__ Bm, int ldb,
                                                const float* __restrict__ bias,
                                                float* __restrict__ C,
                                                int M, int N, int K) {
    __shared__ float As[16][128];   // k-major (transposed) for b128 frag reads
    __shared__ float Bs[16][128];
    int m0 = blockIdx.x * 128, n0 = blockIdx.y * 128;
    int tid = threadIdx.x;
    int lr = tid & 127;             // tile row for staging
    int lq = tid >> 7;              // which k-half (8 cols) this thread stages
    int tn = (tid & 15) * 8;        // thread's n offset (frag)
    int tm = (tid >> 4) * 8;        // thread's m offset (frag)

    const float* Aptr = A + (size_t)(m0 + lr) * lda + lq * 8;
    const float* Bptr = Bm + (size_t)(n0 + lr) * ldb + lq * 8;
    bool bvalid = (EPI == 0) || (n0 + lr) < N;

    float acc[8][8] = {};

    for (int k0 = 0; k0 < K; k0 += 16) {
        float4 a0 = *(const float4*)(Aptr + k0);
        float4 a1 = *(const float4*)(Aptr + k0 + 4);
        float4 b0 = make_float4(0.f, 0.f, 0.f, 0.f), b1 = b0;
        if (bvalid) {
            b0 = *(const float4*)(Bptr + k0);
            b1 = *(const float4*)(Bptr + k0 + 4);
        }
        __syncthreads();   // previous iteration's LDS reads complete
        int kb = lq * 8;
        As[kb + 0][lr] = a0.x; As[kb + 1][lr] = a0.y; As[kb + 2][lr] = a0.z; As[kb + 3][lr] = a0.w;
        As[kb + 4][lr] = a1.x; As[kb + 5][lr] = a1.y; As[kb + 6][lr] = a1.z; As[kb + 7][lr] = a1.w;
        Bs[kb + 0][lr] = b0.x; Bs[kb + 1][lr] = b0.y; Bs[kb + 2][lr] = b0.z; Bs[kb + 3][lr] = b0.w;
        Bs[kb + 4][lr] = b1.x; Bs[kb + 5][lr] = b1.y; Bs[kb + 6][lr] = b1.z; Bs[kb + 7][lr] = b1.w;
        __syncthreads();
#pragma unroll
        for (int kk = 0; kk < 16; ++kk) {
            float4 af0 = *(const float4*)&As[kk][tm];
            float4 af1 = *(const float4*)&As[kk][tm + 4];
            float4 bf0 = *(const float4*)&Bs[kk][tn];
            float4 bf1 = *(const float4*)&Bs[kk][tn + 4];
            float av[8] = {af0.x, af0.y, af0.z, af0.w, af1.x, af1.y, af1.z, af1.w};
            float bv[8] = {bf0.x, bf0.y, bf0.z, bf0.w, bf1.x, bf1.y, bf1.z, bf1.w};
#pragma unroll
            for (int i = 0; i < 8; ++i)
#pragma unroll
                for (int j = 0; j < 8; ++j)
                    acc[i][j] += av[i] * bv[j];
        }
    }

#pragma unroll
    for (int i = 0; i < 8; ++i) {
        int m = m0 + tm + i;
        if (EPI == 0) {
            const float* rb = bias + (size_t)(m & 127) * N;
            float* crow = C + (size_t)m * N;
#pragma unroll
            for (int jq = 0; jq < 8; jq += 4) {
                int n = n0 + tn + jq;
                float4 r = *(const float4*)(rb + n);
                float4 v = make_float4(acc[i][jq] + r.x, acc[i][jq + 1] + r.y,
                                       acc[i][jq + 2] + r.z, acc[i][jq + 3] + r.w);
                *(float4*)(crow + n) = v;
            }
        } else {
            int t = m >> 7, b = m & 127;
            float* orow = C + (size_t)b * T_ * V_ + (size_t)t * V_;
#pragma unroll
            for (int jq = 0; jq < 8; jq += 4) {
                int n = n0 + tn + jq;
                if (n + 3 < N) {
                    float4 r = *(const float4*)(bias + n);
                    float4 v = make_float4(acc[i][jq] + r.x, acc[i][jq + 1] + r.y,
                                           acc[i][jq + 2] + r.z, acc[i][jq + 3] + r.w);
                    *(float4*)(orow + n) = v;
                } else {
#pragma unroll
                    for (int j = 0; j < 4; ++j)
                        if (n + j < N) orow[n + j] = acc[i][jq + j] + bias[n + j];
                }
            }
        }
    }
}

// ---------------------------------------------------------------------------
// One LSTM step, fully fused: gates GEMM (+gx +b_hh) + sigmoid/tanh + c/h update
// grid (16 b-groups, 16 h-groups), block 256.
// Block covers 8 batches x 64 h-cols x 4 gates (= 256 gate columns).
// Thread: 1 gate column x 8 batches; h_prev tile staged in LDS (uniform reads).
// ---------------------------------------------------------------------------
__global__ __launch_bounds__(256) void lstm_step_kernel(const float* __restrict__ h_prev,
                                                        const float* __restrict__ c_prev,
                                                        const float* __restrict__ gx_t,
                                                        const float* __restrict__ w_hh,
                                                        const float* __restrict__ b_hh,
                                                        float* __restrict__ h_out,
                                                        float* __restrict__ c_out) {
    __shared__ float hs8[8][H_];     // 32 KB
    __shared__ float gsm[8][256];    // 8 KB gate exchange
    int bg = blockIdx.x * 8;
    int h0 = blockIdx.y * 64;
    int tid = threadIdx.x;

    for (int i = tid; i < 8 * (H_ / 4); i += 256) {
        int b = i >> 8, k4 = i & 255;          // H_/4 == 256
        ((float4*)hs8[b])[k4] = ((const float4*)(h_prev + (size_t)(bg + b) * H_))[k4];
    }
    __syncthreads();

    int gate = tid >> 6, hh = tid & 63;
    int g = gate * H_ + h0 + hh;
    const float* wr = w_hh + (size_t)g * H_;
    float acc[8] = {};
    for (int k = 0; k < H_; k += 4) {
        float4 w = *(const float4*)(wr + k);
#pragma unroll
        for (int b = 0; b < 8; ++b) {
            float4 h4 = *(const float4*)&hs8[b][k];   // uniform address: broadcast
            acc[b] += w.x * h4.x + w.y * h4.y + w.z * h4.z + w.w * h4.w;
        }
    }
    float bb = b_hh[g];
#pragma unroll
    for (int b = 0; b < 8; ++b)
        gsm[b][tid] = acc[b] + bb + gx_t[(size_t)(bg + b) * G4_ + g];
    __syncthreads();

    for (int j = tid; j < 512; j += 256) {     // 8 b x 64 h updates
        int b = j >> 6, hloc = j & 63;
        float iv = gsm[b][hloc];
        float fv = gsm[b][64 + hloc];
        float gv = gsm[b][128 + hloc];
        float ov = gsm[b][192 + hloc];
        iv = 1.f / (1.f + expf(-iv));
        fv = 1.f / (1.f + expf(-fv));
        gv = tanhf(gv);
        ov = 1.f / (1.f + expf(-ov));
        int bi = bg + b, hcol = h0 + hloc;
        float c = fv * c_prev[(size_t)bi * H_ + hcol] + iv * gv;
        float hv = ov * tanhf(c);
        c_out[(size_t)bi * H_ + hcol] = c;
        h_out[(size_t)bi * H_ + hcol] = hv;
    }
}

// ---------------------------------------------------------------------------
extern "C" void kernel_launch(void* const* d_in, const int* in_sizes, int n_in,
                              void* d_out, int out_size, void* d_ws, size_t ws_size,
                              hipStream_t stream) {
    const float* X        = (const float*)d_in[0];
    const int*   labels   = (const int*)d_in[1];
    const float* fembed_w = (const float*)d_in[2];
    const float* fembed_b = (const float*)d_in[3];
    const float* lembed   = (const float*)d_in[4];
    const float* w_ih     = (const float*)d_in[5];
    const float* b_ih     = (const float*)d_in[6];
    const float* w_hh     = (const float*)d_in[7];
    const float* b_hh     = (const float*)d_in[8];
    const float* lin_w    = (const float*)d_in[9];
    const float* lin_b    = (const float*)d_in[10];
    float* out = (float*)d_out;

    // workspace layout (all fp32); total ~114 MiB
    char* ws = (char*)d_ws;
    float* hs_full = (float*)ws; ws += (size_t)(T_ + 1) * B_ * H_ * 4;  // [41][128][1024]
    float* cbuf    = (float*)ws; ws += (size_t)2 * B_ * H_ * 4;         // ping-pong c
    float* feats   = (float*)ws; ws += (size_t)B_ * E_ * 4;
    float* gfeat   = (float*)ws; ws += (size_t)B_ * G4_ * 4;
    float* emb     = (float*)ws; ws += (size_t)T_ * B_ * E_ * 4;        // [m=t*128+b][512]
    float* gx      = (float*)ws; ws += (size_t)T_ * B_ * G4_ * 4;       // [t][b][4096]

    // t=0 state is zero (ws is poisoned 0xAA by harness)
    zero_kernel<<<512, 256, 0, stream>>>(hs_full, cbuf);

    feats_kernel<<<dim3(B_, 2), 256, 0, stream>>>(X, fembed_w, fembed_b, feats);
    gfeat_kernel<<<dim3(16, 16), 256, 0, stream>>>(feats, w_ih, b_ih, gfeat);
    gather_kernel<<<T_ * B_, 128, 0, stream>>>(labels, lembed, emb);

    // gx[m][g] = emb[m] . w_ih[g][512:1024] + gfeat[m%128][g]
    gemm_f32<0><<<dim3(40, 32), 256, 0, stream>>>(emb, E_, w_ih + E_, 2 * E_,
                                                  gfeat, gx, T_ * B_, G4_, E_);

    for (int t = 0; t < T_; ++t) {
        lstm_step_kernel<<<dim3(16, 16), 256, 0, stream>>>(
            hs_full + (size_t)t * B_ * H_,
            cbuf + (size_t)(t & 1) * B_ * H_,
            gx + (size_t)t * B_ * G4_,
            w_hh, b_hh,
            hs_full + (size_t)(t + 1) * B_ * H_,
            cbuf + (size_t)((t + 1) & 1) * B_ * H_);
    }

    // predicts[b][t][v] = hs[t][b] . lin_w[v] + lin_b[v]
    gemm_f32<1><<<dim3(40, 79), 256, 0, stream>>>(hs_full + (size_t)B_ * H_, H_,
                                                  lin_w, H_, lin_b, out,
                                                  T_ * B_, V_, H_);
}

// Round 4
// 1007.563 us; speedup vs baseline: 3.7113x; 3.7113x over previous
//
#include <hip/hip_runtime.h>

#define B_   128
#define T_   40
#define E_   512
#define H_   1024
#define V_   10000
#define IN_  2048
#define G4_  4096
#define NPAD 10112   // 79 * 128

typedef __attribute__((ext_vector_type(8))) short bf16x8;
typedef __attribute__((ext_vector_type(4))) float f32x4;

__device__ inline unsigned short f2bf(float x) {
    unsigned u = __float_as_uint(x);
    u += 0x7fff + ((u >> 16) & 1);          // RNE
    return (unsigned short)(u >> 16);
}
__device__ inline float bf2f(unsigned short u) {
    return __uint_as_float(((unsigned)u) << 16);
}
__device__ inline float sigf(float x) { return 1.f / (1.f + __expf(-x)); }
__device__ inline float tanhfast(float x) {
    x = fminf(fmaxf(x, -15.f), 15.f);
    float e = __expf(2.f * x);
    return (e - 1.f) / (e + 1.f);
}

// ---------------------------------------------------------------------------
// Stage ROWSx64 bf16 tile global -> LDS via global_load_lds(16B).
// LDS dest linear chunk c = row*8 + kc; global source chunk pre-swizzled
// (kc ^= row&7) so the swizzled frag() ds_read_b128 is bank-conflict-free
// (2-way max per 16-lane phase). src points at (row0, k0); ld in elements.
// ---------------------------------------------------------------------------
template <int NINST>   // NINST = rows/64: 2 -> 128 rows, 1 -> 64 rows
__device__ inline void stageT(const unsigned short* __restrict__ src, int ld,
                              char* lbuf, int wave, int lane) {
#pragma unroll
    for (int i = 0; i < NINST * 2; ++i) {
        int c = i * 256 + wave * 64 + lane;
        int row = c >> 3, kc = c & 7;
        const unsigned short* g = src + (size_t)row * ld + ((kc ^ (row & 7)) << 3);
        __builtin_amdgcn_global_load_lds(
            (const __attribute__((address_space(1))) void*)g,
            (__attribute__((address_space(3))) void*)(lbuf + ((i * 256 + wave * 64) << 4)),
            16, 0, 0);
    }
}
// swizzled frag read: row-major [R][64] bf16 tile, 8 bf16 at (row, kc*8)
__device__ inline bf16x8 frag(const char* base, int row, int kc) {
    return *(const bf16x8*)(base + (((row << 3) + (kc ^ (row & 7))) << 4));
}

// ---------------------------------------------------------------------------
// bf16 MFMA GEMM: C = A[M][K] * B[N][K]^T (+bias), 128x128 tile, BK=64,
// 4 waves (2x2, 64x64 each), double-buffered global_load_lds (1 barrier/K-step).
// EPI 0 (gx):     gx_bf[m][n] = bf16(acc + gfeatB[m&127][n])   (bf16 out!)
// EPI 1 (logits): out[b][t][n] = acc + lin_b[n], m = t*128+b, guard n < V_
// ---------------------------------------------------------------------------
template <int EPI>
__global__ __launch_bounds__(256) void gemm_bf16(const unsigned short* __restrict__ A, int lda,
                                                 const unsigned short* __restrict__ Bm, int ldb,
                                                 const float* __restrict__ bias,
                                                 void* __restrict__ Cout, int K) {
    __shared__ char lds[67584];   // union: 2x(16K A + 16K B) staging | 128x132 f32 exchange
    int m0 = blockIdx.x * 128, n0 = blockIdx.y * 128;
    int tid = threadIdx.x, lane = tid & 63, wave = tid >> 6;
    int wm = (wave >> 1) * 64, wn = (wave & 1) * 64;
    const unsigned short* Ab = A + (size_t)m0 * lda;
    const unsigned short* Bb = Bm + (size_t)n0 * ldb;

    f32x4 acc[4][4];
#pragma unroll
    for (int i = 0; i < 4; ++i)
#pragma unroll
        for (int j = 0; j < 4; ++j) acc[i][j] = (f32x4){0.f, 0.f, 0.f, 0.f};

    stageT<2>(Ab, lda, lds, wave, lane);
    stageT<2>(Bb, ldb, lds + 16384, wave, lane);
    __syncthreads();

    int nk = K >> 6;
    for (int kt = 0; kt < nk; ++kt) {
        int cur = kt & 1;
        if (kt + 1 < nk) {
            stageT<2>(Ab + ((kt + 1) << 6), lda, lds + (cur ^ 1) * 32768, wave, lane);
            stageT<2>(Bb + ((kt + 1) << 6), ldb, lds + (cur ^ 1) * 32768 + 16384, wave, lane);
        }
        const char* Ac = lds + cur * 32768;
        const char* Bc = Ac + 16384;
#pragma unroll
        for (int kk = 0; kk < 2; ++kk) {
            int kc = (kk << 2) + (lane >> 4);
            bf16x8 af[4], bfr[4];
#pragma unroll
            for (int i = 0; i < 4; ++i) af[i] = frag(Ac, wm + i * 16 + (lane & 15), kc);
#pragma unroll
            for (int j = 0; j < 4; ++j) bfr[j] = frag(Bc, wn + j * 16 + (lane & 15), kc);
#pragma unroll
            for (int i = 0; i < 4; ++i)
#pragma unroll
                for (int j = 0; j < 4; ++j)
                    acc[i][j] = __builtin_amdgcn_mfma_f32_16x16x32_bf16(af[i], bfr[j], acc[i][j], 0, 0, 0);
        }
        __syncthreads();
    }

    // ---- epilogue: D-frags -> LDS exchange -> coalesced stores ----
    float(*ex)[132] = (float(*)[132])lds;
#pragma unroll
    for (int i = 0; i < 4; ++i) {
        int r = wm + i * 16 + (lane >> 4) * 4;     // D: row = (l>>4)*4 + reg
#pragma unroll
        for (int j = 0; j < 4; ++j) {
            int c = wn + j * 16 + (lane & 15);     // D: col = l&15
#pragma unroll
            for (int q = 0; q < 4; ++q) ex[r + q][c] = acc[i][j][q];
        }
    }
    __syncthreads();
#pragma unroll
    for (int it = 0; it < 16; ++it) {
        int chunk = it * 256 + tid;
        int r = chunk >> 5, c4 = (chunk & 31) << 2;
        float4 v = *(const float4*)&ex[r][c4];
        if (EPI == 0) {
            const float* gb = bias + (((size_t)((m0 + r) & 127)) << 12) + (n0 + c4);
            float4 b4 = *(const float4*)gb;
            ushort4 u = {f2bf(v.x + b4.x), f2bf(v.y + b4.y),
                         f2bf(v.z + b4.z), f2bf(v.w + b4.w)};
            *(ushort4*)((unsigned short*)Cout + (((size_t)(m0 + r)) << 12) + n0 + c4) = u;
        } else {
            int n = n0 + c4;
            if (n < V_) {
                float4 b4 = *(const float4*)(bias + n);
                v.x += b4.x; v.y += b4.y; v.z += b4.z; v.w += b4.w;
                int m = m0 + r, tt = m >> 7, b = m & 127;
                *(float4*)((float*)Cout + ((size_t)b * T_ + tt) * V_ + n) = v;
            }
        }
    }
}

// ---------------------------------------------------------------------------
// Fused LSTM step: gates = gx_t + h_prev @ w_hh^T (bf16 MFMA, fp32 acc),
// then sigmoid/tanh + c/h update fully in-register (no cross-lane exchange).
// 64 blocks; block = all 128 batches x 16 h-cols x 4 gates (64 tile cols).
// Waves tile 32(M) x 64(N); acc[i][j] IS gate j, hcol = hc0 + (lane&15).
// wperm row d = blk*64 + r holds w_hh row (r>>4)*1024 + blk*16 + (r&15).
// ---------------------------------------------------------------------------
__global__ __launch_bounds__(256) void lstm_step(const unsigned short* __restrict__ hprev,
                                                 const float* __restrict__ cprev,
                                                 const unsigned short* __restrict__ gx_t,
                                                 const unsigned short* __restrict__ wperm,
                                                 unsigned short* __restrict__ hout,
                                                 float* __restrict__ cout) {
    __shared__ char lds[49152];   // 2 x (16K A + 8K B)
    int tid = threadIdx.x, lane = tid & 63, wave = tid >> 6;
    int hc0 = blockIdx.x << 4;
    const unsigned short* Bb = wperm + ((size_t)blockIdx.x << 16);   // 64 rows * 1024
    int wm = wave << 5;

    stageT<2>(hprev, H_, lds, wave, lane);
    stageT<1>(Bb, H_, lds + 16384, wave, lane);

    f32x4 acc[2][4];          // init from gx_t (accumulator carries the input-gate part)
#pragma unroll
    for (int i = 0; i < 2; ++i) {
        int rb = wm + i * 16 + (lane >> 4) * 4;
#pragma unroll
        for (int j = 0; j < 4; ++j) {
            int g = (j << 10) + hc0 + (lane & 15);
#pragma unroll
            for (int q = 0; q < 4; ++q)
                acc[i][j][q] = bf2f(gx_t[(((size_t)(rb + q)) << 12) + g]);
        }
    }
    __syncthreads();

    for (int kt = 0; kt < 16; ++kt) {
        int cur = kt & 1;
        if (kt < 15) {
            stageT<2>(hprev + ((kt + 1) << 6), H_, lds + (cur ^ 1) * 24576, wave, lane);
            stageT<1>(Bb + ((kt + 1) << 6), H_, lds + (cur ^ 1) * 24576 + 16384, wave, lane);
        }
        const char* Ac = lds + cur * 24576;
        const char* Bc = Ac + 16384;
#pragma unroll
        for (int kk = 0; kk < 2; ++kk) {
            int kc = (kk << 2) + (lane >> 4);
            bf16x8 af[2], bfr[4];
#pragma unroll
            for (int i = 0; i < 2; ++i) af[i] = frag(Ac, wm + i * 16 + (lane & 15), kc);
#pragma unroll
            for (int j = 0; j < 4; ++j) bfr[j] = frag(Bc, j * 16 + (lane & 15), kc);
#pragma unroll
            for (int i = 0; i < 2; ++i)
#pragma unroll
                for (int j = 0; j < 4; ++j)
                    acc[i][j] = __builtin_amdgcn_mfma_f32_16x16x32_bf16(af[i], bfr[j], acc[i][j], 0, 0, 0);
        }
        __syncthreads();
    }

    int hcol = hc0 + (lane & 15);
#pragma unroll
    for (int i = 0; i < 2; ++i) {
        int rb = wm + i * 16 + (lane >> 4) * 4;
        f32x4 iv4 = acc[i][0], fv4 = acc[i][1], gv4 = acc[i][2], ov4 = acc[i][3];
#pragma unroll
        for (int q = 0; q < 4; ++q) {
            int b = rb + q;
            float iv = sigf(iv4[q]);
            float fv = sigf(fv4[q]);
            float gv = tanhfast(gv4[q]);
            float ov = sigf(ov4[q]);
            float c = fv * cprev[(((size_t)b) << 10) + hcol] + iv * gv;
            float hv = ov * tanhfast(c);
            cout[(((size_t)b) << 10) + hcol] = c;
            hout[(((size_t)b) << 10) + hcol] = f2bf(hv);
        }
    }
}

// ---------------------------------------------------------------------------
// prep kernels
// ---------------------------------------------------------------------------
__global__ __launch_bounds__(256) void zero_init(unsigned short* h0, float* c0) {
    int i = blockIdx.x * 256 + threadIdx.x;       // 512 blocks -> 131072
    h0[i] = 0;
    c0[i] = 0.f;
}

__global__ __launch_bounds__(256) void feats_kernel(const float* __restrict__ X,
                                                    const float* __restrict__ W,
                                                    const float* __restrict__ bias,
                                                    float* __restrict__ out) {
    __shared__ float xs[IN_];
    int b = blockIdx.x, eg = blockIdx.y;
    const float4* xr = (const float4*)(X + (size_t)b * IN_);
    for (int i = threadIdx.x; i < IN_ / 4; i += 256) ((float4*)xs)[i] = xr[i];
    __syncthreads();
    int e = eg * 256 + threadIdx.x;
    const float* wr = W + (size_t)e * IN_;
    float acc = 0.f;
#pragma unroll 4
    for (int k = 0; k < IN_; k += 4) {
        float4 w = *(const float4*)(wr + k);
        acc += w.x * xs[k] + w.y * xs[k + 1] + w.z * xs[k + 2] + w.w * xs[k + 3];
    }
    out[(size_t)b * E_ + e] = acc + bias[e];
}

// gfeatB[b][g] = feats[b] . w_ih[g][0:512] + b_ih[g] + b_hh[g]
__global__ __launch_bounds__(256) void gfeatB_kernel(const float* __restrict__ feats,
                                                     const float* __restrict__ w_ih,
                                                     const float* __restrict__ b_ih,
                                                     const float* __restrict__ b_hh,
                                                     float* __restrict__ gfeatB) {
    __shared__ float fs[8][E_];
    int bg = blockIdx.x * 8, gg = blockIdx.y * 256;
    for (int i = threadIdx.x; i < 8 * E_ / 4; i += 256) {
        int b = i / (E_ / 4), k4 = i % (E_ / 4);
        ((float4*)fs[b])[k4] = ((const float4*)(feats + (size_t)(bg + b) * E_))[k4];
    }
    __syncthreads();
    int g = gg + threadIdx.x;
    const float* wr = w_ih + (size_t)g * (2 * E_);
    float acc[8] = {};
    for (int k = 0; k < E_; k += 4) {
        float4 w = *(const float4*)(wr + k);
#pragma unroll
        for (int b = 0; b < 8; ++b) {
            float4 f = *(const float4*)&fs[b][k];
            acc[b] += w.x * f.x + w.y * f.y + w.z * f.z + w.w * f.w;
        }
    }
    float bb = b_ih[g] + b_hh[g];
#pragma unroll
    for (int b = 0; b < 8; ++b)
        gfeatB[(size_t)(bg + b) * G4_ + g] = acc[b] + bb;
}

// emb_bf[m][0:512] = bf16(lembed[labels[b][t]]), m = t*128+b
__global__ __launch_bounds__(128) void gather_bf(const int* __restrict__ labels,
                                                 const float* __restrict__ lembed,
                                                 unsigned short* __restrict__ emb) {
    int m = blockIdx.x, t = m >> 7, b = m & 127;
    int lab = labels[b * T_ + t];
    int c = threadIdx.x * 4;
    float4 v = *(const float4*)(lembed + (size_t)lab * E_ + c);
    ushort4 u = {f2bf(v.x), f2bf(v.y), f2bf(v.z), f2bf(v.w)};
    *(ushort4*)(emb + (size_t)m * E_ + c) = u;
}

// lin_w [10000][1024] f32 -> [10112][1024] bf16, zero-padded rows
__global__ __launch_bounds__(256) void conv_pad_lin(const float* __restrict__ w,
                                                    unsigned short* __restrict__ o) {
    int r = blockIdx.x, c = threadIdx.x * 4;
    float4 v = make_float4(0.f, 0.f, 0.f, 0.f);
    if (r < V_) v = *(const float4*)(w + (size_t)r * H_ + c);
    ushort4 u = {f2bf(v.x), f2bf(v.y), f2bf(v.z), f2bf(v.w)};
    *(ushort4*)(o + (size_t)r * H_ + c) = u;
}

// w_hh [4096][1024] -> wperm bf16: dst row d = blk*64 + r holds
// w_hh row (r>>4)*1024 + blk*16 + (r&15)
__global__ __launch_bounds__(256) void conv_whh(const float* __restrict__ w,
                                                unsigned short* __restrict__ o) {
    int d = blockIdx.x, blk = d >> 6, r = d & 63;
    int s = ((r >> 4) << 10) + (blk << 4) + (r & 15);
    int c = threadIdx.x * 4;
    float4 v = *(const float4*)(w + (size_t)s * H_ + c);
    ushort4 u = {f2bf(v.x), f2bf(v.y), f2bf(v.z), f2bf(v.w)};
    *(ushort4*)(o + (size_t)d * H_ + c) = u;
}

// w_ih cols 512..1023 -> w_ihe bf16 [4096][512]
__global__ __launch_bounds__(128) void conv_wih(const float* __restrict__ w,
                                                unsigned short* __restrict__ o) {
    int g = blockIdx.x, c = threadIdx.x * 4;
    float4 v = *(const float4*)(w + (size_t)g * (2 * E_) + E_ + c);
    ushort4 u = {f2bf(v.x), f2bf(v.y), f2bf(v.z), f2bf(v.w)};
    *(ushort4*)(o + (size_t)g * E_ + c) = u;
}

// ---------------------------------------------------------------------------
extern "C" void kernel_launch(void* const* d_in, const int* in_sizes, int n_in,
                              void* d_out, int out_size, void* d_ws, size_t ws_size,
                              hipStream_t stream) {
    const float* X        = (const float*)d_in[0];
    const int*   labels   = (const int*)d_in[1];
    const float* fembed_w = (const float*)d_in[2];
    const float* fembed_b = (const float*)d_in[3];
    const float* lembed   = (const float*)d_in[4];
    const float* w_ih     = (const float*)d_in[5];
    const float* b_ih     = (const float*)d_in[6];
    const float* w_hh     = (const float*)d_in[7];
    const float* b_hh     = (const float*)d_in[8];
    const float* lin_w    = (const float*)d_in[9];
    const float* lin_b    = (const float*)d_in[10];
    float* out = (float*)d_out;

    // workspace layout (~95 MiB; round-1 proved >= ~119 MiB exists)
    char* ws = (char*)d_ws;
    unsigned short* hs_bf  = (unsigned short*)ws; ws += (size_t)(T_ + 1) * B_ * H_ * 2;
    float*          cbuf   = (float*)ws;          ws += (size_t)2 * B_ * H_ * 4;
    float*          feats  = (float*)ws;          ws += (size_t)B_ * E_ * 4;
    float*          gfeatB = (float*)ws;          ws += (size_t)B_ * G4_ * 4;
    unsigned short* emb_bf = (unsigned short*)ws; ws += (size_t)T_ * B_ * E_ * 2;
    unsigned short* w_ihe  = (unsigned short*)ws; ws += (size_t)G4_ * E_ * 2;
    unsigned short* wperm  = (unsigned short*)ws; ws += (size_t)G4_ * H_ * 2;
    unsigned short* lin_wp = (unsigned short*)ws; ws += (size_t)NPAD * H_ * 2;
    unsigned short* gx     = (unsigned short*)ws; ws += (size_t)T_ * B_ * G4_ * 2;

    // prep (independent)
    zero_init<<<512, 256, 0, stream>>>(hs_bf, cbuf);
    conv_whh<<<G4_, 256, 0, stream>>>(w_hh, wperm);
    conv_wih<<<G4_, 128, 0, stream>>>(w_ih, w_ihe);
    conv_pad_lin<<<NPAD, 256, 0, stream>>>(lin_w, lin_wp);
    gather_bf<<<T_ * B_, 128, 0, stream>>>(labels, lembed, emb_bf);
    feats_kernel<<<dim3(B_, 2), 256, 0, stream>>>(X, fembed_w, fembed_b, feats);
    gfeatB_kernel<<<dim3(16, 16), 256, 0, stream>>>(feats, w_ih, b_ih, b_hh, gfeatB);

    // gx[m][g] = bf16(emb_bf[m] . w_ihe[g] + gfeatB[m&127][g])  (M=5120,N=4096,K=512)
    gemm_bf16<0><<<dim3(40, 32), 256, 0, stream>>>(emb_bf, E_, w_ihe, E_, gfeatB, gx, E_);

    for (int t = 0; t < T_; ++t) {
        lstm_step<<<64, 256, 0, stream>>>(
            hs_bf + (size_t)t * B_ * H_,
            cbuf + (size_t)(t & 1) * B_ * H_,
            gx + (size_t)t * B_ * G4_,
            wperm,
            hs_bf + (size_t)(t + 1) * B_ * H_,
            cbuf + (size_t)((t + 1) & 1) * B_ * H_);
    }

    // logits: out[b][t][v] = hs_bf[t+1][b] . lin_wp[v] + lin_b[v]
    gemm_bf16<1><<<dim3(40, 79), 256, 0, stream>>>(hs_bf + (size_t)B_ * H_, H_,
                                                   lin_wp, H_, lin_b, out, H_);
}